// Round 13
// baseline (759.962 us; speedup 1.0000x reference)
//
#include <hip/hip_runtime.h>
#include <hip/hip_bf16.h>

#define B_TOK 16384
#define TOPK 2
#define NEXP 64
#define HID 512
#define FFN 1024
#define NASSIGN (B_TOK * TOPK)   // 32768
#define CAP (NASSIGN / NEXP)     // 512 assignments per expert (balanced)

typedef unsigned short u16;
typedef __bf16 bf16_t;
typedef bf16_t bf16x8 __attribute__((ext_vector_type(8)));
typedef float f32x4 __attribute__((ext_vector_type(4)));

// native cvt: compiler emits v_cvt_pk_bf16_f32 (RTNE)
__device__ __forceinline__ unsigned pkbf(float a, float b) {
  union { bf16_t h[2]; unsigned u; } v;
  v.h[0] = (bf16_t)a; v.h[1] = (bf16_t)b;
  return v.u;
}
__device__ __forceinline__ u16 f2bf(float f) {
  union { bf16_t h; u16 u; } v; v.h = (bf16_t)f; return v.u;
}
__device__ __forceinline__ float bf2f(unsigned u16v) {
  union { unsigned u; float f; } v; v.u = u16v << 16; return v.f;
}

#define GLOAD_LDS16(g, l)                                                     \
  __builtin_amdgcn_global_load_lds((const __attribute__((address_space(1))) void*)(g), \
                                   (__attribute__((address_space(3))) void*)(l), 16, 0, 0)

// ---------------------------------------------------------------- routing
__global__ void k_route(const int* __restrict__ ids, int* __restrict__ cnt,
                        int* __restrict__ tok_of, int* __restrict__ slot_pos) {
  int n = blockIdx.x * blockDim.x + threadIdx.x;
  if (n >= NASSIGN) return;
  int e = ids[n];
  int r = atomicAdd(&cnt[e], 1);
  int p = e * CAP + r;
  tok_of[p] = n >> 1;
  slot_pos[n] = p;
}

// ------------------------------------------------- gather + fp32->bf16 cast
__global__ void k_gather(const float* __restrict__ hs, const int* __restrict__ tok_of,
                         u16* __restrict__ Xg) {
  int p = blockIdx.x * 4 + (threadIdx.x >> 6);
  int lane = threadIdx.x & 63;
  const float4* src = reinterpret_cast<const float4*>(hs + (size_t)tok_of[p] * HID);
  uint2* dst = reinterpret_cast<uint2*>(Xg + (size_t)p * HID);
#pragma unroll
  for (int i = 0; i < 2; i++) {
    float4 v = src[i * 64 + lane];
    uint2 o;
    o.x = pkbf(v.x, v.y);
    o.y = pkbf(v.z, v.w);
    dst[i * 64 + lane] = o;
  }
}

// ------------------------------------------------------------ grouped GEMM
// C[e*CAP+m][n] = sum_k A[e*CAP+m][k] * W[e][k][n]; W fp32 transposed+cvt to
// bf16 LDS in-kernel.  128x128 tile, BK=32, 4 waves (2x2), dbuf A+B.
// Depth-2 L-prefetch: two L register sets (float2[8], static indices); iter t
//   1. frag ds_reads (cur bufs)
//   2. STAGE_A(t+1) DMA -> opposite bufA  (readers passed last barrier)
//   3. WRITE_B(t+1) from L set loaded a FULL iter ago (no stall) -> opp bufB
//   4. LOAD_L(t+2) into the freed set (2-iter flight)
//   5. 16 MFMA
//   6. s_waitcnt vmcnt(8) lgkmcnt(0) + raw s_barrier -- retires A-DMA(t+1)
//      (older) while the 8 L(t+2) loads stay in flight (never drain to 0).
// LDS layout (A and B identical; R11-verified, 0 conflicts): logical
// (row r, chunk c in 0..3) at byte (r>>1)*128 + ((4*(r&1)+c)^((r>>1)&7))*16.
template <int K, int NN, bool SILU>
__global__ __launch_bounds__(256, 4) void k_gemm(const u16* __restrict__ A,
                                                 const float* __restrict__ Wf,
                                                 u16* __restrict__ Cout) {
  constexpr int MT = CAP / 128;        // 4
  constexpr int NT = NN / 128;         // 8 (G1) / 4 (G2)
  constexpr int NWG = NEXP * MT * NT;  // %8 == 0
  constexpr int Qx = NWG / 8;
  constexpr int KT = K / 32;           // 16 / 32 (even)
  int wg = (blockIdx.x % 8) * Qx + blockIdx.x / 8;  // XCD chunked swizzle
  int e = wg / (MT * NT);
  int rm = wg % (MT * NT);
  int mt = rm / NT, nt = rm % NT;

  const u16* Ab = A + ((size_t)e * CAP + (size_t)mt * 128) * K;

  // LDS: A dbuf 2x8KB at 0; B dbuf 2x8KB at 16384. 32KB.
  __shared__ __align__(16) char smc[32768];

  int t_ = threadIdx.x;
  int lane = t_ & 63, wv = t_ >> 6;
  int wm = wv >> 1, wn = wv & 1;        // 2x2 wave grid; wave out = 64x64
  int l15 = lane & 15, lhi = lane >> 4;

  // ---- A staging: DMA call j writes phys chunks m = t_ + 256*j linearly.
  // Decode phys m -> logical (r,c):  pair=m>>3, x=(m&7)^(pair&7),
  // r=2*pair+(x>>2), c=x&3.  Source = Ab + r*K + c*8 (+ tile k offset).
  int pr0 = t_ >> 3, x0 = (t_ & 7) ^ (pr0 & 7);
  int m1 = t_ + 256;
  int pr1 = m1 >> 3, x1 = (m1 & 7) ^ (pr1 & 7);
  const u16* gA0 = Ab + (size_t)(2 * pr0 + (x0 >> 2)) * K + (x0 & 3) * 8;
  const u16* gA1 = Ab + (size_t)(2 * pr1 + (x1 >> 2)) * K + (x1 & 3) * 8;
#define STAGE_A(tn)                                                          \
  do {                                                                       \
    char* d_ = smc + ((tn) & 1) * 8192 + wv * 1024;                          \
    GLOAD_LDS16(gA0 + (size_t)(tn) * 32, d_);                                \
    GLOAD_LDS16(gA1 + (size_t)(tn) * 32, d_ + 4096);                         \
  } while (0)

  // ---- B staging: thread owns cols n=2*lane, 2*lane+1; k-chunk kg=wv
  int kg = wv;
  const float* gWb = Wf + (size_t)e * K * NN + (size_t)(kg * 8) * NN +
                     (size_t)nt * 128 + lane * 2;
  int wb0 = 16384 + lane * 128 + ((kg) ^ (lane & 7)) * 16;       // col 2*lane
  int wb1 = 16384 + lane * 128 + ((4 + kg) ^ (lane & 7)) * 16;   // col 2*lane+1
  // two L register sets (depth-2 pipeline); static indices only
  float2 LA[8], LB[8];
#define LOAD_L(P, tn)                                                        \
  do {                                                                       \
    const float* g_ = gWb + (size_t)(tn) * 32 * NN;                          \
    P[0] = *reinterpret_cast<const float2*>(g_);                             \
    P[1] = *reinterpret_cast<const float2*>(g_ + (size_t)1 * NN);            \
    P[2] = *reinterpret_cast<const float2*>(g_ + (size_t)2 * NN);            \
    P[3] = *reinterpret_cast<const float2*>(g_ + (size_t)3 * NN);            \
    P[4] = *reinterpret_cast<const float2*>(g_ + (size_t)4 * NN);            \
    P[5] = *reinterpret_cast<const float2*>(g_ + (size_t)5 * NN);            \
    P[6] = *reinterpret_cast<const float2*>(g_ + (size_t)6 * NN);            \
    P[7] = *reinterpret_cast<const float2*>(g_ + (size_t)7 * NN);            \
  } while (0)
#define WRITE_B(P, tn)                                                       \
  do {                                                                       \
    char* w_ = smc + ((tn) & 1) * 8192;                                      \
    uint4 v0, v1;                                                            \
    v0.x = pkbf(P[0].x, P[1].x); v0.y = pkbf(P[2].x, P[3].x);                \
    v0.z = pkbf(P[4].x, P[5].x); v0.w = pkbf(P[6].x, P[7].x);                \
    v1.x = pkbf(P[0].y, P[1].y); v1.y = pkbf(P[2].y, P[3].y);                \
    v1.z = pkbf(P[4].y, P[5].y); v1.w = pkbf(P[6].y, P[7].y);                \
    *reinterpret_cast<uint4*>(w_ + wb0) = v0;                                \
    *reinterpret_cast<uint4*>(w_ + wb1) = v1;                                \
  } while (0)

  f32x4 acc[4][4];
#pragma unroll
  for (int i = 0; i < 4; i++)
#pragma unroll
    for (int j = 0; j < 4; j++) {
      f32x4 z = {0.f, 0.f, 0.f, 0.f};
      acc[i][j] = z;
    }
  bf16x8 a[4], b[4];

  // ---- fragment read offsets (swizzled layout; R11-verified)
  int aof[4], bof[4];
#pragma unroll
  for (int f = 0; f < 4; f++) {
    int ar = wm * 64 + f * 16 + l15;
    aof[f] = (ar >> 1) * 128 + (((ar & 1) * 4 + lhi) ^ ((ar >> 1) & 7)) * 16;
    int br = wn * 64 + f * 16 + l15;
    bof[f] = 16384 + (br >> 1) * 128 + (((br & 1) * 4 + lhi) ^ ((br >> 1) & 7)) * 16;
  }

  // iteration body; SETW = L set for WRITE_B(t+1), SETL = set refilled L(t+2)
#define ITER(t, SETW, SETL)                                                  \
  do {                                                                       \
    const char* pb = smc + ((t) & 1) * 8192;                                 \
    _Pragma("unroll") for (int f = 0; f < 4; f++) {                          \
      a[f] = *reinterpret_cast<const bf16x8*>(pb + aof[f]);                  \
      b[f] = *reinterpret_cast<const bf16x8*>(pb + bof[f]);                  \
    }                                                                        \
    if ((t) + 1 < KT) {                                                      \
      STAGE_A((t) + 1);                                                      \
      WRITE_B(SETW, (t) + 1);  /* L regs landed ~1 iter ago */               \
    }                                                                        \
    if ((t) + 2 < KT) LOAD_L(SETL, (t) + 2);                                 \
    _Pragma("unroll") for (int mf = 0; mf < 4; mf++)                         \
        _Pragma("unroll") for (int nf = 0; nf < 4; nf++)                     \
            acc[mf][nf] = __builtin_amdgcn_mfma_f32_16x16x32_bf16(           \
                a[mf], b[nf], acc[mf][nf], 0, 0, 0);                         \
    if ((t) + 2 < KT)                                                        \
      asm volatile("s_waitcnt vmcnt(8) lgkmcnt(0)" ::: "memory");            \
    else                                                                     \
      asm volatile("s_waitcnt vmcnt(0) lgkmcnt(0)" ::: "memory");            \
    __builtin_amdgcn_sched_barrier(0);                                       \
    __builtin_amdgcn_s_barrier();                                            \
  } while (0)

  // ---- prologue: A(0) DMA; L(0)->WRITE_B(0); L(1) stays in flight
  STAGE_A(0);
  LOAD_L(LA, 0);
  asm volatile("s_waitcnt vmcnt(0)" ::: "memory");  // L(0) regs + A(0) resident
  __builtin_amdgcn_sched_barrier(0);
  WRITE_B(LA, 0);
  LOAD_L(LB, 1);                                    // 8 loads left in flight
  asm volatile("s_waitcnt lgkmcnt(0)" ::: "memory");
  __builtin_amdgcn_sched_barrier(0);
  __builtin_amdgcn_s_barrier();

  for (int tt = 0; tt < KT; tt += 2) {
    ITER(tt, LB, LA);      // even t: write from set B (L(t+1)), refill set A
    ITER(tt + 1, LA, LB);  // odd  t: write from set A, refill set B
  }
#undef ITER
#undef STAGE_A
#undef LOAD_L
#undef WRITE_B

  // epilogue: D row = lhi*4+reg, col = l15 (verified C/D layout); bf16 out
#pragma unroll
  for (int mf = 0; mf < 4; mf++) {
#pragma unroll
    for (int nf = 0; nf < 4; nf++) {
#pragma unroll
      for (int rg = 0; rg < 4; rg++) {
        float v = acc[mf][nf][rg];
        int grow = mt * 128 + wm * 64 + mf * 16 + lhi * 4 + rg;
        int gcol = nt * 128 + wn * 64 + nf * 16 + l15;
        size_t off = ((size_t)e * CAP + grow) * NN + gcol;
        if constexpr (SILU) v = v / (1.0f + __expf(-v));  // silu
        Cout[off] = f2bf(v);
      }
    }
  }
}

// ------------------------------------------- weighted combine (no atomics)
// wave per token: lane reads uint4 (8 bf16) per slot row, writes 2 float4.
__global__ void k_combine(const u16* __restrict__ yws, const int* __restrict__ slot_pos,
                          const float* __restrict__ w, float* __restrict__ out) {
  int tk = blockIdx.x * 4 + (threadIdx.x >> 6);
  int lane = threadIdx.x & 63;
  int p0 = slot_pos[2 * tk], p1 = slot_pos[2 * tk + 1];
  float w0 = w[2 * tk], w1 = w[2 * tk + 1];
  uint4 ua = reinterpret_cast<const uint4*>(yws + (size_t)p0 * HID)[lane];
  uint4 ub = reinterpret_cast<const uint4*>(yws + (size_t)p1 * HID)[lane];
  float4 o0, o1;
  o0.x = w0 * bf2f(ua.x & 0xffffu) + w1 * bf2f(ub.x & 0xffffu);
  o0.y = w0 * bf2f(ua.x >> 16) + w1 * bf2f(ub.x >> 16);
  o0.z = w0 * bf2f(ua.y & 0xffffu) + w1 * bf2f(ub.y & 0xffffu);
  o0.w = w0 * bf2f(ua.y >> 16) + w1 * bf2f(ub.y >> 16);
  o1.x = w0 * bf2f(ua.z & 0xffffu) + w1 * bf2f(ub.z & 0xffffu);
  o1.y = w0 * bf2f(ua.z >> 16) + w1 * bf2f(ub.z >> 16);
  o1.z = w0 * bf2f(ua.w & 0xffffu) + w1 * bf2f(ub.w & 0xffffu);
  o1.w = w0 * bf2f(ua.w >> 16) + w1 * bf2f(ub.w >> 16);
  float4* dst = reinterpret_cast<float4*>(out + (size_t)tk * HID + lane * 8);
  dst[0] = o0;
  dst[1] = o1;
}

// ---------------------------------------------------------------- launcher
extern "C" void kernel_launch(void* const* d_in, const int* in_sizes, int n_in,
                              void* d_out, int out_size, void* d_ws, size_t ws_size,
                              hipStream_t stream) {
  const float* hs = (const float*)d_in[0];
  const float* wts = (const float*)d_in[1];
  const int* ids = (const int*)d_in[2];
  const float* W1 = (const float*)d_in[3];
  const float* W2 = (const float*)d_in[4];
  float* out = (float*)d_out;

  char* ws = (char*)d_ws;
  size_t o = 0;
  int* cnt = (int*)(ws + o);       o += 1024;
  int* slot_pos = (int*)(ws + o);  o += (size_t)NASSIGN * 4;
  int* tok_of = (int*)(ws + o);    o += (size_t)NASSIGN * 4;
  o = (o + 255) & ~(size_t)255;
  u16* Xg = (u16*)(ws + o);        o += (size_t)NASSIGN * HID * 2;      // 32 MB
  u16* hid = (u16*)(ws + o);       o += (size_t)NASSIGN * FFN * 2;      // 64 MB
  u16* yws = (u16*)(ws + o);       o += (size_t)NASSIGN * HID * 2;      // 32 MB

  hipMemsetAsync(cnt, 0, NEXP * sizeof(int), stream);
  k_route<<<(NASSIGN + 255) / 256, 256, 0, stream>>>(ids, cnt, tok_of, slot_pos);
  k_gather<<<NASSIGN / 4, 256, 0, stream>>>(hs, tok_of, Xg);
  k_gemm<HID, FFN, true><<<NEXP * (CAP / 128) * (FFN / 128), 256, 0, stream>>>(Xg, W1, hid);
  k_gemm<FFN, HID, false><<<NEXP * (CAP / 128) * (HID / 128), 256, 0, stream>>>(hid, W2, yws);
  k_combine<<<B_TOK / 4, 256, 0, stream>>>(yws, slot_pos, wts, out);
}

// Round 14
// 269.484 us; speedup vs baseline: 2.8201x; 2.8201x over previous
//
#include <hip/hip_runtime.h>
#include <hip/hip_bf16.h>

#define B_TOK 16384
#define TOPK 2
#define NEXP 64
#define HID 512
#define FFN 1024
#define NASSIGN (B_TOK * TOPK)   // 32768
#define CAP (NASSIGN / NEXP)     // 512 assignments per expert (balanced)

typedef unsigned short u16;
typedef __bf16 bf16_t;
typedef bf16_t bf16x8 __attribute__((ext_vector_type(8)));
typedef float f32x4 __attribute__((ext_vector_type(4)));

// native cvt: compiler emits v_cvt_pk_bf16_f32 (RTNE)
__device__ __forceinline__ unsigned pkbf(float a, float b) {
  union { bf16_t h[2]; unsigned u; } v;
  v.h[0] = (bf16_t)a; v.h[1] = (bf16_t)b;
  return v.u;
}
__device__ __forceinline__ u16 f2bf(float f) {
  union { bf16_t h; u16 u; } v; v.h = (bf16_t)f; return v.u;
}
__device__ __forceinline__ float bf2f(unsigned u16v) {
  union { unsigned u; float f; } v; v.u = u16v << 16; return v.f;
}

#define GLOAD_LDS16(g, l)                                                     \
  __builtin_amdgcn_global_load_lds((const __attribute__((address_space(1))) void*)(g), \
                                   (__attribute__((address_space(3))) void*)(l), 16, 0, 0)

// ---------------------------------------------------------------- routing
__global__ void k_route(const int* __restrict__ ids, int* __restrict__ cnt,
                        int* __restrict__ tok_of, int* __restrict__ slot_pos) {
  int n = blockIdx.x * blockDim.x + threadIdx.x;
  if (n >= NASSIGN) return;
  int e = ids[n];
  int r = atomicAdd(&cnt[e], 1);
  int p = e * CAP + r;
  tok_of[p] = n >> 1;
  slot_pos[n] = p;
}

// ------------------------------------------------- gather + fp32->bf16 cast
__global__ void k_gather(const float* __restrict__ hs, const int* __restrict__ tok_of,
                         u16* __restrict__ Xg) {
  int p = blockIdx.x * 4 + (threadIdx.x >> 6);
  int lane = threadIdx.x & 63;
  const float4* src = reinterpret_cast<const float4*>(hs + (size_t)tok_of[p] * HID);
  uint2* dst = reinterpret_cast<uint2*>(Xg + (size_t)p * HID);
#pragma unroll
  for (int i = 0; i < 2; i++) {
    float4 v = src[i * 64 + lane];
    uint2 o;
    o.x = pkbf(v.x, v.y);
    o.y = pkbf(v.z, v.w);
    dst[i * 64 + lane] = o;
  }
}

// --------------------------------- per-expert transpose + fp32->bf16 cast
// in: [E][R][C] fp32 ; out: [E][C][R] bf16.  64x64 tiles (R5-proven).
template <int R, int C>
__global__ void k_transpose_bf16(const float* __restrict__ in, u16* __restrict__ out) {
  __shared__ float tile[64][65];
  int e = blockIdx.z;
  int c0 = blockIdx.x * 64;
  int r0 = blockIdx.y * 64;
  const float* src = in + (size_t)e * R * C;
  u16* dst = out + (size_t)e * R * C;
  int tx = threadIdx.x & 63, ty = threadIdx.x >> 6;  // ty 0..3
#pragma unroll
  for (int p = 0; p < 16; p++) {
    int r = p * 4 + ty;
    tile[r][tx] = src[(size_t)(r0 + r) * C + (c0 + tx)];
  }
  __syncthreads();
  int rO = threadIdx.x >> 2, seg = threadIdx.x & 3;
  unsigned pk[8];
#pragma unroll
  for (int j = 0; j < 8; j++) {
    float a = tile[seg * 16 + 2 * j][rO];
    float b = tile[seg * 16 + 2 * j + 1][rO];
    pk[j] = pkbf(a, b);
  }
  uint4* dp = reinterpret_cast<uint4*>(dst + (size_t)(c0 + rO) * R + r0 + seg * 16);
  dp[0] = make_uint4(pk[0], pk[1], pk[2], pk[3]);
  dp[1] = make_uint4(pk[4], pk[5], pk[6], pk[7]);
}

// ------------------------------------------------------------ grouped GEMM
// C[e*CAP+m][n] = sum_k A[e*CAP+m][k] * Bw[e][n][k]  (both bf16, k-contig).
// R7's proven 256x256/BK=64/8-wave 4-phase skeleton; B's reg-path replaced by
// pure global_load_lds DMA (mirrors A).  Per K-tile:
//  ph0: ds_read a03(8)+b01(4); STAGE_B(t+1,h0);  lgkm0 bar; Q(0,0); bar
//  ph1: ds_read b23(4);        STAGE_B(t+1,h1);  lgkm0 bar; Q(0,1); bar
//  ph2: ds_read a47(8);                          lgkm0 bar; Q(1,0); bar
//  ph3: STAGE_A(t+2,h0+h1) (cur slot -- all A-reads drained at ph2 bar);
//       vmcnt(4) [retires A(t+1)+B(t+1); A(t+2) stays in flight]; bar;
//       Q(1,1); bar
// Swizzle (rule #21 both-sides, A and B identical): 8 chunks/128B row,
// phys chunk = c ^ (row&7); pre-swizzled global source, linear DMA dest.
template <int K, int NN, bool SILU>
__global__ __launch_bounds__(512, 2) void k_gemm(const u16* __restrict__ A,
                                                 const u16* __restrict__ Bw,
                                                 u16* __restrict__ Cout) {
  constexpr int MT = CAP / 256;        // 2
  constexpr int NT = NN / 256;
  constexpr int NWG = NEXP * MT * NT;  // %8 == 0
  constexpr int Q = NWG / 8;
  constexpr int KT = K / 64;           // 8 or 16
  int wg = (blockIdx.x % 8) * Q + blockIdx.x / 8;  // XCD chunked swizzle
  int e = wg / (MT * NT);
  int rm = wg % (MT * NT);
  int mt = rm / NT, nt = rm % NT;

  const u16* Ab = A + ((size_t)e * CAP + (size_t)mt * 256) * K;
  const u16* Bb = Bw + (size_t)e * NN * K + (size_t)nt * 256 * K;

  // LDS: A dbuf 2x32KB at 0; B dbuf 2x32KB at 65536. 128KB.
  __shared__ __align__(16) char smc[131072];

  int t_ = threadIdx.x;
  int lane = t_ & 63, wv = t_ >> 6;
  int wm = wv >> 2, wn = wv & 3;        // 2x4 wave grid; wave out = 128x64
  int l15 = lane & 15, lhi = lane >> 4;

  // ---- staging: row t_>>3 (0..63/call), chunk pos t_&7, src chunk ^(row&7)
  int srow = t_ >> 3;
  int gchunk = (t_ & 7) ^ (srow & 7);
  const u16* gA = Ab + (size_t)srow * K + gchunk * 8;
  const u16* gB = Bb + (size_t)srow * K + gchunk * 8;
#define STAGE_HALF_A(tn, j)                                                  \
  do {                                                                       \
    char* d_ = smc + ((tn) & 1) * 32768 + (j) * 16384 + wv * 1024;           \
    const u16* s_ = gA + (size_t)((j) * 128) * K + (tn) * 64;                \
    GLOAD_LDS16(s_, d_);                                                     \
    GLOAD_LDS16(s_ + (size_t)64 * K, d_ + 8192);                             \
  } while (0)
#define STAGE_HALF_B(tn, j)                                                  \
  do {                                                                       \
    char* d_ = smc + 65536 + ((tn) & 1) * 32768 + (j) * 16384 + wv * 1024;   \
    const u16* s_ = gB + (size_t)((j) * 128) * K + (tn) * 64;                \
    GLOAD_LDS16(s_, d_);                                                     \
    GLOAD_LDS16(s_ + (size_t)64 * K, d_ + 8192);                             \
  } while (0)

  f32x4 acc[8][4];
#pragma unroll
  for (int i = 0; i < 8; i++)
#pragma unroll
    for (int j = 0; j < 4; j++) {
      f32x4 z = {0.f, 0.f, 0.f, 0.f};
      acc[i][j] = z;
    }
  bf16x8 a[4][2], b[4][2];

  // ---- fragment read offsets: off = row*128 + ((x*4+lhi)^(row&7))*16,
  // row&7 == l15&7 for all frag rows (offsets are multiples of 8 rows).
  int aof0 = (wm * 128 + l15) * 128 + ((lhi ^ (l15 & 7)) << 4);
  int aof1 = (wm * 128 + l15) * 128 + (((4 + lhi) ^ (l15 & 7)) << 4);
  int boff[4][2];
#pragma unroll
  for (int nf = 0; nf < 4; nf++) {
    int r = wn * 64 + nf * 16 + l15;
    boff[nf][0] = r * 128 + ((lhi ^ (l15 & 7)) << 4);
    boff[nf][1] = r * 128 + (((4 + lhi) ^ (l15 & 7)) << 4);
  }

#define LGKM0_BAR()                                                          \
  do {                                                                       \
    asm volatile("s_waitcnt lgkmcnt(0)" ::: "memory");                       \
    __builtin_amdgcn_sched_barrier(0);                                       \
    __builtin_amdgcn_s_barrier();                                            \
  } while (0)

#define MFMA_QUAD(mh, nh)                                                    \
  do {                                                                       \
    __builtin_amdgcn_s_setprio(1);                                           \
    _Pragma("unroll") for (int mf = 0; mf < 4; mf++)                         \
        _Pragma("unroll") for (int nf = 0; nf < 2; nf++)                     \
            _Pragma("unroll") for (int kk = 0; kk < 2; kk++)                 \
                acc[(mh)*4 + mf][(nh)*2 + nf] = __builtin_amdgcn_mfma_f32_16x16x32_bf16( \
                    a[mf][kk], b[(nh)*2 + nf][kk], acc[(mh)*4 + mf][(nh)*2 + nf], 0, 0, 0); \
    __builtin_amdgcn_s_setprio(0);                                           \
  } while (0)

  // ---- prologue: A(0), B(0), A(1); vmcnt(4) retires A(0)+B(0)
  STAGE_HALF_A(0, 0); STAGE_HALF_A(0, 1);
  STAGE_HALF_B(0, 0); STAGE_HALF_B(0, 1);
  if (KT > 1) {
    STAGE_HALF_A(1, 0); STAGE_HALF_A(1, 1);
    asm volatile("s_waitcnt vmcnt(4)" ::: "memory");
  } else {
    asm volatile("s_waitcnt vmcnt(0)" ::: "memory");
  }
  __builtin_amdgcn_sched_barrier(0);
  __builtin_amdgcn_s_barrier();

  for (int t = 0; t < KT; t++) {
    const char* pA = smc + (t & 1) * 32768;
    const char* pB = smc + 65536 + (t & 1) * 32768;

    // ---------------- phase 0: frags a03 + b01; stage B(t+1) h0
#pragma unroll
    for (int mf = 0; mf < 4; mf++) {
      a[mf][0] = *reinterpret_cast<const bf16x8*>(pA + aof0 + mf * 2048);
      a[mf][1] = *reinterpret_cast<const bf16x8*>(pA + aof1 + mf * 2048);
    }
#pragma unroll
    for (int nf = 0; nf < 2; nf++) {
      b[nf][0] = *reinterpret_cast<const bf16x8*>(pB + boff[nf][0]);
      b[nf][1] = *reinterpret_cast<const bf16x8*>(pB + boff[nf][1]);
    }
    if (t + 1 < KT) STAGE_HALF_B(t + 1, 0);
    LGKM0_BAR();
    MFMA_QUAD(0, 0);
    __builtin_amdgcn_s_barrier();

    // ---------------- phase 1: frags b23; stage B(t+1) h1
#pragma unroll
    for (int nf = 0; nf < 2; nf++) {
      b[2 + nf][0] = *reinterpret_cast<const bf16x8*>(pB + boff[2 + nf][0]);
      b[2 + nf][1] = *reinterpret_cast<const bf16x8*>(pB + boff[2 + nf][1]);
    }
    if (t + 1 < KT) STAGE_HALF_B(t + 1, 1);
    LGKM0_BAR();
    MFMA_QUAD(0, 1);
    __builtin_amdgcn_s_barrier();

    // ---------------- phase 2: frags a47 (all A-reads of tile t done here)
#pragma unroll
    for (int mf = 0; mf < 4; mf++) {
      a[mf][0] = *reinterpret_cast<const bf16x8*>(pA + aof0 + (4 + mf) * 2048);
      a[mf][1] = *reinterpret_cast<const bf16x8*>(pA + aof1 + (4 + mf) * 2048);
    }
    LGKM0_BAR();
    MFMA_QUAD(1, 0);
    __builtin_amdgcn_s_barrier();

    // ---------------- phase 3: A(t+2) DMA into cur slot; counted vmcnt
    if (t + 2 < KT) { STAGE_HALF_A(t + 2, 0); STAGE_HALF_A(t + 2, 1); }
    if (t + 1 < KT) {
      if (t + 2 < KT)
        asm volatile("s_waitcnt vmcnt(4)" ::: "memory");  // A(t+1)+B(t+1) done
      else
        asm volatile("s_waitcnt vmcnt(0)" ::: "memory");  // tail drain
    }
    __builtin_amdgcn_sched_barrier(0);
    __builtin_amdgcn_s_barrier();
    MFMA_QUAD(1, 1);
    __builtin_amdgcn_s_barrier();
  }
#undef STAGE_HALF_A
#undef STAGE_HALF_B
#undef MFMA_QUAD
#undef LGKM0_BAR

  // epilogue: D row = lhi*4+reg, col = l15 (verified C/D layout); bf16 out
#pragma unroll
  for (int mf = 0; mf < 8; mf++) {
#pragma unroll
    for (int nf = 0; nf < 4; nf++) {
#pragma unroll
      for (int rg = 0; rg < 4; rg++) {
        float v = acc[mf][nf][rg];
        int grow = mt * 256 + wm * 128 + mf * 16 + lhi * 4 + rg;
        int gcol = nt * 256 + wn * 64 + nf * 16 + l15;
        size_t off = ((size_t)e * CAP + grow) * NN + gcol;
        if constexpr (SILU) v = v / (1.0f + __expf(-v));  // silu
        Cout[off] = f2bf(v);
      }
    }
  }
}

// ------------------------------------------- weighted combine (no atomics)
// wave per token: lane reads uint4 (8 bf16) per slot row, writes 2 float4.
__global__ void k_combine(const u16* __restrict__ yws, const int* __restrict__ slot_pos,
                          const float* __restrict__ w, float* __restrict__ out) {
  int tk = blockIdx.x * 4 + (threadIdx.x >> 6);
  int lane = threadIdx.x & 63;
  int p0 = slot_pos[2 * tk], p1 = slot_pos[2 * tk + 1];
  float w0 = w[2 * tk], w1 = w[2 * tk + 1];
  uint4 ua = reinterpret_cast<const uint4*>(yws + (size_t)p0 * HID)[lane];
  uint4 ub = reinterpret_cast<const uint4*>(yws + (size_t)p1 * HID)[lane];
  float4 o0, o1;
  o0.x = w0 * bf2f(ua.x & 0xffffu) + w1 * bf2f(ub.x & 0xffffu);
  o0.y = w0 * bf2f(ua.x >> 16) + w1 * bf2f(ub.x >> 16);
  o0.z = w0 * bf2f(ua.y & 0xffffu) + w1 * bf2f(ub.y & 0xffffu);
  o0.w = w0 * bf2f(ua.y >> 16) + w1 * bf2f(ub.y >> 16);
  o1.x = w0 * bf2f(ua.z & 0xffffu) + w1 * bf2f(ub.z & 0xffffu);
  o1.y = w0 * bf2f(ua.z >> 16) + w1 * bf2f(ub.z >> 16);
  o1.z = w0 * bf2f(ua.w & 0xffffu) + w1 * bf2f(ub.w & 0xffffu);
  o1.w = w0 * bf2f(ua.w >> 16) + w1 * bf2f(ub.w >> 16);
  float4* dst = reinterpret_cast<float4*>(out + (size_t)tk * HID + lane * 8);
  dst[0] = o0;
  dst[1] = o1;
}

// ---------------------------------------------------------------- launcher
extern "C" void kernel_launch(void* const* d_in, const int* in_sizes, int n_in,
                              void* d_out, int out_size, void* d_ws, size_t ws_size,
                              hipStream_t stream) {
  const float* hs = (const float*)d_in[0];
  const float* wts = (const float*)d_in[1];
  const int* ids = (const int*)d_in[2];
  const float* W1 = (const float*)d_in[3];
  const float* W2 = (const float*)d_in[4];
  float* out = (float*)d_out;

  char* ws = (char*)d_ws;
  size_t o = 0;
  int* cnt = (int*)(ws + o);       o += 1024;
  int* slot_pos = (int*)(ws + o);  o += (size_t)NASSIGN * 4;
  int* tok_of = (int*)(ws + o);    o += (size_t)NASSIGN * 4;
  o = (o + 255) & ~(size_t)255;
  u16* Xg = (u16*)(ws + o);        o += (size_t)NASSIGN * HID * 2;      // 32 MB
  u16* hid = (u16*)(ws + o);       o += (size_t)NASSIGN * FFN * 2;      // 64 MB
  u16* yws = (u16*)(ws + o);       o += (size_t)NASSIGN * HID * 2;      // 32 MB
  u16* W1T = (u16*)(ws + o);       o += (size_t)NEXP * HID * FFN * 2;   // 64 MB
  u16* W2T = (u16*)(ws + o);       o += (size_t)NEXP * HID * FFN * 2;   // 64 MB

  hipMemsetAsync(cnt, 0, NEXP * sizeof(int), stream);
  k_route<<<(NASSIGN + 255) / 256, 256, 0, stream>>>(ids, cnt, tok_of, slot_pos);
  k_gather<<<NASSIGN / 4, 256, 0, stream>>>(hs, tok_of, Xg);
  k_transpose_bf16<HID, FFN><<<dim3(FFN / 64, HID / 64, NEXP), 256, 0, stream>>>(W1, W1T);
  k_transpose_bf16<FFN, HID><<<dim3(HID / 64, FFN / 64, NEXP), 256, 0, stream>>>(W2, W2T);
  k_gemm<HID, FFN, true><<<NEXP * (CAP / 256) * (FFN / 256), 512, 0, stream>>>(Xg, W1T, hid);
  k_gemm<FFN, HID, false><<<NEXP * (CAP / 256) * (HID / 256), 512, 0, stream>>>(hid, W2T, yws);
  k_combine<<<B_TOK / 4, 256, 0, stream>>>(yws, slot_pos, wts, out);
}

// Round 15
// 215.040 us; speedup vs baseline: 3.5340x; 1.2532x over previous
//
#include <hip/hip_runtime.h>
#include <hip/hip_bf16.h>

#define B_TOK 16384
#define TOPK 2
#define NEXP 64
#define HID 512
#define FFN 1024
#define NASSIGN (B_TOK * TOPK)   // 32768
#define CAP (NASSIGN / NEXP)     // 512 assignments per expert (balanced)

typedef unsigned short u16;
typedef __bf16 bf16_t;
typedef bf16_t bf16x8 __attribute__((ext_vector_type(8)));
typedef float f32x4 __attribute__((ext_vector_type(4)));

// native cvt: compiler emits v_cvt_pk_bf16_f32 (RTNE)
__device__ __forceinline__ unsigned pkbf(float a, float b) {
  union { bf16_t h[2]; unsigned u; } v;
  v.h[0] = (bf16_t)a; v.h[1] = (bf16_t)b;
  return v.u;
}
__device__ __forceinline__ u16 f2bf(float f) {
  union { bf16_t h; u16 u; } v; v.h = (bf16_t)f; return v.u;
}
__device__ __forceinline__ float bf2f(unsigned u16v) {
  union { unsigned u; float f; } v; v.u = u16v << 16; return v.f;
}

#define GLOAD_LDS16(g, l)                                                     \
  __builtin_amdgcn_global_load_lds((const __attribute__((address_space(1))) void*)(g), \
                                   (__attribute__((address_space(3))) void*)(l), 16, 0, 0)

// ---------------------------------------------------------------- routing
__global__ void k_route(const int* __restrict__ ids, int* __restrict__ cnt,
                        int* __restrict__ tok_of, int* __restrict__ slot_pos) {
  int n = blockIdx.x * blockDim.x + threadIdx.x;
  if (n >= NASSIGN) return;
  int e = ids[n];
  int r = atomicAdd(&cnt[e], 1);
  int p = e * CAP + r;
  tok_of[p] = n >> 1;       // token index for sorted slot p
  slot_pos[n] = p;          // inverse map: assignment n -> sorted slot
}

// ------------------------------------------------- gather + fp32->bf16 cast
__global__ void k_gather(const float* __restrict__ hs, const int* __restrict__ tok_of,
                         u16* __restrict__ Xg) {
  int p = blockIdx.x * 4 + (threadIdx.x >> 6);
  int lane = threadIdx.x & 63;
  const float4* src = reinterpret_cast<const float4*>(hs + (size_t)tok_of[p] * HID);
  uint2* dst = reinterpret_cast<uint2*>(Xg + (size_t)p * HID);
#pragma unroll
  for (int i = 0; i < 2; i++) {
    float4 v = src[i * 64 + lane];
    uint2 o;
    o.x = pkbf(v.x, v.y);
    o.y = pkbf(v.z, v.w);
    dst[i * 64 + lane] = o;
  }
}

// ------------------------------------------------------------ grouped GEMM
// R7-verbatim (best verified): C[e*CAP+m][n] = sum_k A[.][k] * W[e][k][n],
// W fp32 transposed+cvt to bf16 [n][k] LDS tiles in-kernel (no prepass).
// 256x256 tile, BK=64, 8 waves (2Mx4N). Per K-tile, 4 phases:
//  ph0: ds_read a03(8)+b01(4); issue W-loads L0..3(t+1);   lgkm0 bar; Q(0,0); bar
//  ph1: ds_read b23(4);        issue W-loads L4..7(t+1);   lgkm0 bar; Q(0,1); bar
//  ph2: ds_read a47(8);                                    lgkm0 bar; Q(1,0); bar
//  ph3: A(t+2) DMA (all A-reads drained at ph2 bar); vmcnt(4) counted
//       (L0..7 retired, 2-3 phases flight; ADMA stays in flight);
//       4x uint4 swizzled B-writes;                        lgkm0 bar; Q(1,1); bar
// Swizzles (both-sides, rule #21): A chunk c -> c^(row&7) (pre-swizzled global
// source, linear gload_lds dest); B chunk c -> c^S(n), S(n)=(n^(n>>3))&7
// (reg-staged writes), matching ds_read addresses.
template <int K, int NN, bool SILU>
__global__ __launch_bounds__(512, 2) void k_gemm(const u16* __restrict__ A,
                                                 const float* __restrict__ Wf,
                                                 u16* __restrict__ Cout) {
  constexpr int MT = CAP / 256;        // 2
  constexpr int NT = NN / 256;
  constexpr int NWG = NEXP * MT * NT;  // %8 == 0
  constexpr int Q = NWG / 8;
  constexpr int KT = K / 64;           // 8 or 16
  int wg = (blockIdx.x % 8) * Q + blockIdx.x / 8;  // XCD chunked swizzle
  int e = wg / (MT * NT);
  int rm = wg % (MT * NT);
  int mt = rm / NT, nt = rm % NT;

  const u16* Ab = A + ((size_t)e * CAP + (size_t)mt * 256) * K;

  // LDS: A dbuf 2x32KB at 0; B dbuf 2x32KB at 65536. 128KB.
  __shared__ __align__(16) char smc[131072];

  int t_ = threadIdx.x;
  int lane = t_ & 63, wv = t_ >> 6;
  int wm = wv >> 2, wn = wv & 3;        // 2x4 wave grid; wave out = 128x64
  int l15 = lane & 15, lhi = lane >> 4;

  // ---- A staging (global_load_lds): row t_>>3, chunk pos t_&7, src chunk ^row&7
  int srow = t_ >> 3;
  int gchunk = (t_ & 7) ^ (srow & 7);
  const u16* gA = Ab + (size_t)srow * K + gchunk * 8;
#define STAGE_HALF_A(tn, j)                                                  \
  do {                                                                       \
    char* d_ = smc + ((tn) & 1) * 32768 + (j) * 16384 + wv * 1024;           \
    const u16* s_ = gA + (size_t)((j) * 128) * K + (tn) * 64;                \
    GLOAD_LDS16(s_, d_);                                                     \
    GLOAD_LDS16(s_ + (size_t)64 * K, d_ + 8192);                             \
  } while (0)

  // ---- B staging (reg-staged transpose+cvt from fp32 W[k][n])
  int kunit = t_ >> 6;                  // 0..7
  int nunit = t_ & 63;                  // 0..63
  const float* gWb = Wf + (size_t)e * K * NN + (size_t)(kunit * 8) * NN +
                     (size_t)nt * 256 + nunit * 4;
  int wbo[4];                           // byte offsets of the 4 write slots
#pragma unroll
  for (int i = 0; i < 4; i++) {
    int n = nunit * 4 + i;
    int S = (n ^ (n >> 3)) & 7;
    wbo[i] = n * 128 + ((kunit ^ S) << 4);
  }

  f32x4 acc[8][4];
#pragma unroll
  for (int i = 0; i < 8; i++)
#pragma unroll
    for (int j = 0; j < 4; j++) {
      f32x4 z = {0.f, 0.f, 0.f, 0.f};
      acc[i][j] = z;
    }
  bf16x8 a[4][2], b[4][2];

  // ---- fragment read offsets
  int aof0 = (wm * 128 + l15) * 128 + ((lhi ^ (l15 & 7)) << 4);
  int aof1 = (wm * 128 + l15) * 128 + (((4 + lhi) ^ (l15 & 7)) << 4);
  int boff[4][2];
#pragma unroll
  for (int nf = 0; nf < 4; nf++) {
    int r = wn * 64 + nf * 16 + l15;
    int Sr = (r ^ (r >> 3)) & 7;
    boff[nf][0] = r * 128 + ((lhi ^ Sr) << 4);
    boff[nf][1] = r * 128 + (((4 + lhi) ^ Sr) << 4);
  }

#define LGKM0_BAR()                                                          \
  do {                                                                       \
    asm volatile("s_waitcnt lgkmcnt(0)" ::: "memory");                       \
    __builtin_amdgcn_sched_barrier(0);                                       \
    __builtin_amdgcn_s_barrier();                                            \
  } while (0)

#define MFMA_QUAD(mh, nh)                                                    \
  do {                                                                       \
    __builtin_amdgcn_s_setprio(1);                                           \
    _Pragma("unroll") for (int mf = 0; mf < 4; mf++)                         \
        _Pragma("unroll") for (int nf = 0; nf < 2; nf++)                     \
            _Pragma("unroll") for (int kk = 0; kk < 2; kk++)                 \
                acc[(mh)*4 + mf][(nh)*2 + nf] = __builtin_amdgcn_mfma_f32_16x16x32_bf16( \
                    a[mf][kk], b[(nh)*2 + nf][kk], acc[(mh)*4 + mf][(nh)*2 + nf], 0, 0, 0); \
    __builtin_amdgcn_s_setprio(0);                                           \
  } while (0)

  // ---- prologue: A(0), A(1) via DMA; B(0) reg-staged into slot 0
  STAGE_HALF_A(0, 0); STAGE_HALF_A(0, 1);
  if (KT > 1) { STAGE_HALF_A(1, 0); STAGE_HALF_A(1, 1); }
  {
    float4 P[8];
#pragma unroll
    for (int j = 0; j < 8; j++)
      P[j] = *reinterpret_cast<const float4*>(gWb + (size_t)j * NN);
    char* wB = smc + 65536;  // slot 0
#pragma unroll
    for (int i = 0; i < 4; i++) {
      uint4 v;
      v.x = pkbf(P[0][i], P[1][i]); v.y = pkbf(P[2][i], P[3][i]);
      v.z = pkbf(P[4][i], P[5][i]); v.w = pkbf(P[6][i], P[7][i]);
      *reinterpret_cast<uint4*>(wB + wbo[i]) = v;
    }
  }
  asm volatile("s_waitcnt vmcnt(0)" ::: "memory");  // A(0),A(1) resident (once)
  LGKM0_BAR();

  for (int t = 0; t < KT; t++) {
    const char* pA = smc + (t & 1) * 32768;
    const char* pB = smc + 65536 + (t & 1) * 32768;
    char* wB = smc + 65536 + ((t + 1) & 1) * 32768;
    float4 L0, L1, L2, L3, L4, L5, L6, L7;

    // ---------------- phase 0: frags a03+b01; issue L0..3(t+1)
#pragma unroll
    for (int mf = 0; mf < 4; mf++) {
      a[mf][0] = *reinterpret_cast<const bf16x8*>(pA + aof0 + mf * 2048);
      a[mf][1] = *reinterpret_cast<const bf16x8*>(pA + aof1 + mf * 2048);
    }
#pragma unroll
    for (int nf = 0; nf < 2; nf++) {
      b[nf][0] = *reinterpret_cast<const bf16x8*>(pB + boff[nf][0]);
      b[nf][1] = *reinterpret_cast<const bf16x8*>(pB + boff[nf][1]);
    }
    if (t + 1 < KT) {
      const float* g = gWb + (size_t)(t + 1) * 64 * NN;
      L0 = *reinterpret_cast<const float4*>(g);
      L1 = *reinterpret_cast<const float4*>(g + (size_t)1 * NN);
      L2 = *reinterpret_cast<const float4*>(g + (size_t)2 * NN);
      L3 = *reinterpret_cast<const float4*>(g + (size_t)3 * NN);
    }
    LGKM0_BAR();
    MFMA_QUAD(0, 0);
    __builtin_amdgcn_s_barrier();

    // ---------------- phase 1: frags b23; issue L4..7(t+1)
#pragma unroll
    for (int nf = 0; nf < 2; nf++) {
      b[2 + nf][0] = *reinterpret_cast<const bf16x8*>(pB + boff[2 + nf][0]);
      b[2 + nf][1] = *reinterpret_cast<const bf16x8*>(pB + boff[2 + nf][1]);
    }
    if (t + 1 < KT) {
      const float* g = gWb + (size_t)(t + 1) * 64 * NN;
      L4 = *reinterpret_cast<const float4*>(g + (size_t)4 * NN);
      L5 = *reinterpret_cast<const float4*>(g + (size_t)5 * NN);
      L6 = *reinterpret_cast<const float4*>(g + (size_t)6 * NN);
      L7 = *reinterpret_cast<const float4*>(g + (size_t)7 * NN);
    }
    LGKM0_BAR();
    MFMA_QUAD(0, 1);
    __builtin_amdgcn_s_barrier();

    // ---------------- phase 2: frags a47 (all A-reads of tile t done here)
#pragma unroll
    for (int mf = 0; mf < 4; mf++) {
      a[mf][0] = *reinterpret_cast<const bf16x8*>(pA + aof0 + (4 + mf) * 2048);
      a[mf][1] = *reinterpret_cast<const bf16x8*>(pA + aof1 + (4 + mf) * 2048);
    }
    LGKM0_BAR();
    MFMA_QUAD(1, 0);
    __builtin_amdgcn_s_barrier();

    // ---------------- phase 3: A(t+2) DMA; counted vmcnt; uint4 B-writes
    if (t + 2 < KT) { STAGE_HALF_A(t + 2, 0); STAGE_HALF_A(t + 2, 1); }
    if (t + 1 < KT) {
      if (t + 2 < KT)
        asm volatile("s_waitcnt vmcnt(4)" ::: "memory");  // L0..7 retired; ADMA in flight
      else
        asm volatile("s_waitcnt vmcnt(0)" ::: "memory");  // tail
      __builtin_amdgcn_sched_barrier(0);
#pragma unroll
      for (int i = 0; i < 4; i++) {
        uint4 v;
        v.x = pkbf(L0[i], L1[i]); v.y = pkbf(L2[i], L3[i]);
        v.z = pkbf(L4[i], L5[i]); v.w = pkbf(L6[i], L7[i]);
        *reinterpret_cast<uint4*>(wB + wbo[i]) = v;
      }
    }
    LGKM0_BAR();
    MFMA_QUAD(1, 1);
    __builtin_amdgcn_s_barrier();
  }
#undef STAGE_HALF_A
#undef MFMA_QUAD
#undef LGKM0_BAR

  // epilogue: D row = lhi*4+reg, col = l15 (verified C/D layout); bf16 out
#pragma unroll
  for (int mf = 0; mf < 8; mf++) {
#pragma unroll
    for (int nf = 0; nf < 4; nf++) {
#pragma unroll
      for (int rg = 0; rg < 4; rg++) {
        float v = acc[mf][nf][rg];
        int grow = mt * 256 + wm * 128 + mf * 16 + lhi * 4 + rg;
        int gcol = nt * 256 + wn * 64 + nf * 16 + l15;
        size_t off = ((size_t)e * CAP + grow) * NN + gcol;
        if constexpr (SILU) v = v / (1.0f + __expf(-v));  // silu
        Cout[off] = f2bf(v);
      }
    }
  }
}

// ------------------------------------------- weighted combine (no atomics)
// wave per token: lane reads uint4 (8 bf16) per slot row, writes 2 float4.
__global__ void k_combine(const u16* __restrict__ yws, const int* __restrict__ slot_pos,
                          const float* __restrict__ w, float* __restrict__ out) {
  int tk = blockIdx.x * 4 + (threadIdx.x >> 6);
  int lane = threadIdx.x & 63;
  int p0 = slot_pos[2 * tk], p1 = slot_pos[2 * tk + 1];
  float w0 = w[2 * tk], w1 = w[2 * tk + 1];
  uint4 ua = reinterpret_cast<const uint4*>(yws + (size_t)p0 * HID)[lane];
  uint4 ub = reinterpret_cast<const uint4*>(yws + (size_t)p1 * HID)[lane];
  float4 o0, o1;
  o0.x = w0 * bf2f(ua.x & 0xffffu) + w1 * bf2f(ub.x & 0xffffu);
  o0.y = w0 * bf2f(ua.x >> 16) + w1 * bf2f(ub.x >> 16);
  o0.z = w0 * bf2f(ua.y & 0xffffu) + w1 * bf2f(ub.y & 0xffffu);
  o0.w = w0 * bf2f(ua.y >> 16) + w1 * bf2f(ub.y >> 16);
  o1.x = w0 * bf2f(ua.z & 0xffffu) + w1 * bf2f(ub.z & 0xffffu);
  o1.y = w0 * bf2f(ua.z >> 16) + w1 * bf2f(ub.z >> 16);
  o1.z = w0 * bf2f(ua.w & 0xffffu) + w1 * bf2f(ub.w & 0xffffu);
  o1.w = w0 * bf2f(ua.w >> 16) + w1 * bf2f(ub.w >> 16);
  float4* dst = reinterpret_cast<float4*>(out + (size_t)tk * HID + lane * 8);
  dst[0] = o0;
  dst[1] = o1;
}

// ---------------------------------------------------------------- launcher
extern "C" void kernel_launch(void* const* d_in, const int* in_sizes, int n_in,
                              void* d_out, int out_size, void* d_ws, size_t ws_size,
                              hipStream_t stream) {
  const float* hs = (const float*)d_in[0];
  const float* wts = (const float*)d_in[1];
  const int* ids = (const int*)d_in[2];
  const float* W1 = (const float*)d_in[3];
  const float* W2 = (const float*)d_in[4];
  float* out = (float*)d_out;

  char* ws = (char*)d_ws;
  size_t o = 0;
  int* cnt = (int*)(ws + o);       o += 1024;
  int* slot_pos = (int*)(ws + o);  o += (size_t)NASSIGN * 4;
  int* tok_of = (int*)(ws + o);    o += (size_t)NASSIGN * 4;
  o = (o + 255) & ~(size_t)255;
  u16* Xg = (u16*)(ws + o);        o += (size_t)NASSIGN * HID * 2;      // 32 MB
  u16* hid = (u16*)(ws + o);       o += (size_t)NASSIGN * FFN * 2;      // 64 MB
  u16* yws = (u16*)(ws + o);       o += (size_t)NASSIGN * HID * 2;      // 32 MB

  hipMemsetAsync(cnt, 0, NEXP * sizeof(int), stream);
  k_route<<<(NASSIGN + 255) / 256, 256, 0, stream>>>(ids, cnt, tok_of, slot_pos);
  k_gather<<<NASSIGN / 4, 256, 0, stream>>>(hs, tok_of, Xg);
  k_gemm<HID, FFN, true><<<NEXP * (CAP / 256) * (FFN / 256), 512, 0, stream>>>(Xg, W1, hid);
  k_gemm<FFN, HID, false><<<NEXP * (CAP / 256) * (HID / 256), 512, 0, stream>>>(hid, W2, yws);
  k_combine<<<B_TOK / 4, 256, 0, stream>>>(yws, slot_pos, wts, out);
}